// Round 1
// baseline (228.244 us; speedup 1.0000x reference)
//
#include <hip/hip_runtime.h>

#define NB 32768
#define MAXTILE 768
#define ROWS 64
#define NT 4
#define XHS 536            // xh stride in u16: 268 dw ≡ 12 mod 32 → phase-minimal LDS access

typedef short s8v __attribute__((ext_vector_type(8)));   // 8 x bf16 bits (4 VGPR)
typedef short s4v __attribute__((ext_vector_type(4)));
typedef float f4v __attribute__((ext_vector_type(4)));
typedef unsigned short u16;
typedef unsigned short u16x4 __attribute__((ext_vector_type(4)));
typedef unsigned int u32;
typedef unsigned char u8;

__device__ __forceinline__ float bf2f(u16 u) { return __uint_as_float(((u32)u) << 16); }
__device__ __forceinline__ u16 f2bf(float f) {
    u32 x = __float_as_uint(f);
    x += 0x7FFFu + ((x >> 16) & 1u);   // RNE
    return (u16)(x >> 16);
}
__device__ __forceinline__ s8v ld8(const u16* p) { return *reinterpret_cast<const s8v*>(p); }

#define MFMA16(a, b, c) __builtin_amdgcn_mfma_f32_16x16x32_bf16((a), (b), (c), 0, 0, 0)

template <int N> struct IC { static constexpr int v = N; };

// dtype probe, done locally per block (wave 0 ballot -> LDS). bf16=1, f32=0.
__device__ __forceinline__ void detect_flag(const void* input, int tid, int* shflag)
{
    if (tid < 64) {
        u32 w = ((const u32*)input)[tid];
        u32 h0 = w & 0xFFFFu;
        u32 e0 = (h0 >> 7) & 0xFFu;
        bool plaus = (h0 == 0u) || (e0 >= 96u && e0 <= 143u);
        unsigned long long m = __ballot(plaus);
        if (tid == 0) *shflag = (__popcll(m) >= 48) ? 1 : 0;
    }
}

// ---------------------------------------------------------------------------
// dispatch A: blocks [0,128): per-block key histogram -> hist[b][256] (plain
// stores, no global atomics, no memset) + keyloc[row] = key | (rank<<8).
// blocks [128,373): weight repack to A-frag layout + bias conversion.
// ---------------------------------------------------------------------------
struct RepArgs {
    const void* W01; const void* Wp[3]; const void* pre[4]; const void* fin;
    const void* bias[9];
    u16 *rPre, *rW01, *rWp[3], *rFin, *cbias;
};

__global__ __launch_bounds__(256) void prepA_kernel(const void* __restrict__ inputv,
                                                    int* __restrict__ hist,       // [128][256]
                                                    u16* __restrict__ keyloc,     // [NB]
                                                    RepArgs R)
{
    __shared__ int lcnt[256];
    __shared__ u16 T[8192];
    __shared__ int shmisc;
    int tid = threadIdx.x;
    int b = blockIdx.x;
    detect_flag(inputv, tid, &shmisc);
    __syncthreads();
    int flag = shmisc;

    if (b < 128) {
        lcnt[tid] = 0;
        __syncthreads();
        int row = (b << 8) + tid;
        const u32* in32 = (const u32*)inputv;
        const u16* in16 = (const u16*)inputv;
        int key = 0;
        if (flag) {
#pragma unroll
            for (int j = 0; j < 4; j++) {
                u16x4 v = *(const u16x4*)(in16 + row * 144 + 128 + j * 4);
                int m = v[1] ? 1 : (v[2] ? 2 : (v[3] ? 3 : 0));
                key |= m << (j << 1);
            }
        } else {
#pragma unroll
            for (int j = 0; j < 4; j++) {
                const u32* p = in32 + row * 144 + 128 + j * 4;
                u32 v1 = p[1], v2 = p[2], v3 = p[3];
                int m = v1 ? 1 : (v2 ? 2 : (v3 ? 3 : 0));
                key |= m << (j << 1);
            }
        }
        int loc = atomicAdd(&lcnt[key], 1);
        keyloc[row] = (u16)(key | (loc << 8));
        __syncthreads();
        hist[(b << 8) + tid] = lcnt[tid];
        return;
    }

    // ---- repack path
    int rb = b - 128;
    const void* src = nullptr; u16* dst = nullptr; int K = 0, k0 = 0, mrow = 0;
    if (rb < 32) {
        int m = rb >> 3, s = rb & 7;
        src = R.W01; dst = R.rW01 + (m * 8 + s) * 8192; K = 256; k0 = s * 32; mrow = m;
    } else if (rb < 224) {
        int idx = rb - 32, mat = idx >> 6, r = idx & 63, m = r >> 4, s = r & 15;
        src = R.Wp[mat]; dst = R.rWp[mat] + (m * 16 + s) * 8192; K = 512; k0 = s * 32; mrow = m;
    } else if (rb < 240) {
        int idx = rb - 224, mat = idx >> 2, m = idx & 3;
        src = R.pre[mat]; dst = R.rPre + (mat * 4 + m) * 8192; K = 32; k0 = 0; mrow = m;
    } else if (rb < 244) {
        int m = rb - 240;   // Wfin [m][256][8] -> [m][s8][lane][8], rows l16>=8 zero
        const u16* s16 = (const u16*)R.fin;
        const float* s32 = (const float*)R.fin;
        for (int i = tid; i < 2048; i += 256) {
            int si = (m * 256 + (i >> 3)) * 8 + (i & 7);
            T[i] = flag ? s16[si] : f2bf(s32[si]);
        }
        __syncthreads();
        u16* d = R.rFin + m * 4096;
        for (int i = tid; i < 4096; i += 256) {
            int s = i >> 9, lane = (i >> 3) & 63, j = i & 7;
            int q = lane >> 4, l16 = lane & 15;
            int k = s * 32 + q * 8 + j;
            d[i] = (l16 < 8) ? T[k * 8 + l16] : (u16)0;
        }
        return;
    } else {
        const int sz[9] = {1024,1024,1024,1024,1024,1024,1024,1024,32};
        const int of[9] = {0,1024,2048,3072,4096,5120,6144,7168,8192};
        for (int i = tid; i < 8224; i += 256) {
            int t = i, e = 0;
            while (t >= sz[e]) { t -= sz[e]; e++; }
            R.cbias[of[e] + t] = flag ? ((const u16*)R.bias[e])[t]
                                      : f2bf(((const float*)R.bias[e])[t]);
        }
        return;
    }
    const u16* s16 = (const u16*)src;
    const float* s32 = (const float*)src;
    for (int i = tid; i < 8192; i += 256) {
        int k = i >> 8, n = i & 255;
        int srcIdx = (mrow * K + k0 + k) * 256 + n;
        T[i] = flag ? s16[srcIdx] : f2bf(s32[srcIdx]);
    }
    __syncthreads();
    for (int i = tid; i < 8192; i += 256) {
        int mt = i >> 9, lane = (i >> 3) & 63, j = i & 7;
        int k = ((lane >> 4) << 3) + j, n = (mt << 4) + (lane & 15);
        dst[i] = T[(k << 8) + n];
    }
}

// ---------------------------------------------------------------------------
// main: one block = 64 rows through the whole net (T-formulation).
// 8 waves; wave w: m-tiles {2w,2w+1} x 4 n-tiles. Fused K=512 gemm, depth-4
// weight prefetch issued before the barrier. XCD-aware tile swizzle.
//
// NEW: no scatter dispatch. Each block derives its own tile identity
// (key, tau, cnt) and the 64 row ids directly from hist[128][256] + keyloc:
//   phase 1: per-key totals (coalesced column sums) + ONE packed LDS scan
//            (row totals in bits>=12, tile counts in low 12 bits; tile sum
//            <= 764 < 4096 so fields never carry into each other)
//   phase 2: per-hist-block exclusive bases for OUR key (128 loads + scan)
//   phase 3: sweep keyloc (64 coalesced KB), claim rows in [tau*64,tau*64+64)
// Order within a key class is irrelevant (output scattered by row id).
// ---------------------------------------------------------------------------
struct MainP { const u16 *rPre, *rW01, *rWp1, *rWp2, *rWp3, *rFin, *cbias; };

__global__ __launch_bounds__(512, 4) void main_kernel(
    const void* __restrict__ inRaw,
    const int* __restrict__ hist, const u16* __restrict__ keyloc,
    MainP P, void* __restrict__ outp)
{
    __shared__ __align__(16) u16 xh[ROWS * XHS];
    __shared__ int rowids[ROWS];
    __shared__ int shflag;
    __shared__ int sScan[256];
    __shared__ int sBase[128];
    __shared__ int sMeta[3];   // key, tau, tot

    int tid = threadIdx.x;
    int lane = tid & 63, w = tid >> 6, quad = lane >> 4, l16 = lane & 15;

    int b = blockIdx.x;
    int t = ((b & 7) * (MAXTILE / 8)) + (b >> 3);   // XCD-contiguous tile runs

    detect_flag(inRaw, tid, &shflag);

    // ---- phase 1: per-key totals + packed (rows<<12 | tiles) inclusive scan
    int mypack = 0;
    if (tid < 256) {
        int tot = 0;
        for (int b2 = 0; b2 < 128; b2++) tot += hist[(b2 << 8) + tid];
        int tiles = (tot + ROWS - 1) / ROWS;
        mypack = (tot << 12) | tiles;
        sScan[tid] = mypack;
    }
    __syncthreads();
    for (int off = 1; off < 256; off <<= 1) {
        int v = (tid >= off && tid < 256) ? sScan[tid - off] : 0;
        __syncthreads();
        if (tid < 256) sScan[tid] += v;
        __syncthreads();
    }
    if (tid < 256) {
        int tiles = mypack & 0xFFF;
        int tbase = (sScan[tid] & 0xFFF) - tiles;
        if (t >= tbase && t < tbase + tiles) {   // exactly one thread matches
            sMeta[0] = tid;          // key
            sMeta[1] = t - tbase;    // tau
            sMeta[2] = mypack >> 12; // tot
        }
    }
    __syncthreads();
    int ttot = sScan[255] & 0xFFF;
    if (t >= ttot) return;                       // block-uniform exit
    int key = sMeta[0], tau = sMeta[1], tot = sMeta[2];
    int lo = tau * ROWS;
    int cntIn = tot - lo; if (cntIn > ROWS) cntIn = ROWS;

    // ---- phase 2: exclusive per-hist-block base for OUR key
    int myc = 0;
    if (tid < 128) { myc = hist[(tid << 8) + key]; sBase[tid] = myc; }
    if (tid < ROWS) rowids[tid] = 0;             // safe default for partial tiles
    __syncthreads();
    for (int off = 1; off < 128; off <<= 1) {
        int v = (tid >= off && tid < 128) ? sBase[tid - off] : 0;
        __syncthreads();
        if (tid < 128) sBase[tid] += v;
        __syncthreads();
    }
    if (tid < 128) sBase[tid] -= myc;            // inclusive -> exclusive
    __syncthreads();

    // ---- phase 3: claim our rows from keyloc
    {
        int hi = lo + cntIn;
        for (int i = tid; i < NB; i += 512) {
            u32 kl = keyloc[i];
            if ((int)(kl & 255u) == key) {
                int g = sBase[i >> 8] + (int)(kl >> 8);
                if (g >= lo && g < hi) rowids[g - lo] = i;
            }
        }
    }
    __syncthreads();

    int flag = shflag;
    int rows_[NT];
#pragma unroll
    for (int nt = 0; nt < NT; nt++) rows_[nt] = rowids[nt * 16 + l16];

    const u16* in16 = (const u16*)inRaw;
    const float* in32 = (const float*)inRaw;
    int mt0 = w << 1, mt1 = mt0 + 1;

    f4v acc0[NT], acc1[NT];

    // N-slice fused GEMM: prefetch window depth 4, first loads issued BEFORE
    // the hp-visibility barrier (A-frags don't depend on xh).
    auto gemm_run = [&](auto nc, const u16* Ab, int ks0) {
        constexpr int N = decltype(nc)::v;
        constexpr int D = 4;
        const u16* base0 = Ab + mt0 * 512 + lane * 8;
        const u16* base1 = Ab + mt1 * 512 + lane * 8;
        s8v A0[D], A1[D];
#pragma unroll
        for (int d = 0; d < D && d < N; d++) {
            A0[d] = ld8(base0 + d * 8192);
            A1[d] = ld8(base1 + d * 8192);
        }
        __syncthreads();                     // hp/hq now visible; prefetch in flight
#pragma unroll
        for (int s = 0; s < N; s++) {
            s8v c0 = A0[s % D], c1 = A1[s % D];
            if (s + D < N) {
                A0[s % D] = ld8(base0 + (s + D) * 8192);
                A1[s % D] = ld8(base1 + (s + D) * 8192);
            }
#pragma unroll
            for (int nt = 0; nt < NT; nt++) {
                s8v B = ld8(&xh[(nt * 16 + l16) * XHS + (ks0 + s) * 32 + quad * 8]);
                acc0[nt] = MFMA16(c0, B, acc0[nt]);
                acc1[nt] = MFMA16(c1, B, acc1[nt]);
            }
        }
    };

    for (int node = 0; node < 4; node++) {
        int m = (key >> (node << 1)) & 3;

        // ---- feats B-frags: direct gather (128B contiguous per row per node)
        s8v fb[NT];
#pragma unroll
        for (int nt = 0; nt < NT; nt++) {
            int off = rows_[nt] * 144 + (node << 5) + (quad << 3);
            if (flag) fb[nt] = ld8(in16 + off);
            else {
                f4v f0 = *(const f4v*)(in32 + off);
                f4v f1 = *(const f4v*)(in32 + off + 4);
                s8v r;
#pragma unroll
                for (int j = 0; j < 4; j++) { r[j] = (short)f2bf(f0[j]); r[4 + j] = (short)f2bf(f1[j]); }
                fb[nt] = r;
            }
        }

        // ---- hp^T = relu(Wpre^T @ feats^T + bpre) -> xh[.,256..511]
        const u16* preB = P.rPre + ((node << 2) + m) * 8192;
#pragma unroll
        for (int ci = 0; ci < 2; ci++) {
            int mt = mt0 + ci;
            s8v a = ld8(preB + mt * 512 + lane * 8);
            u16x4 bv = *(const u16x4*)(P.cbias + node * 2048 + m * 256 + mt * 16 + quad * 4);
            f4v bias;
#pragma unroll
            for (int r = 0; r < 4; r++) bias[r] = bf2f(bv[r]);
#pragma unroll
            for (int nt = 0; nt < NT; nt++) {
                f4v c = MFMA16(a, fb[nt], bias);
                s4v p;
#pragma unroll
                for (int r = 0; r < 4; r++) { float v = c[r] > 0.f ? c[r] : 0.f; p[r] = (short)f2bf(v); }
                *(s4v*)&xh[(nt * 16 + l16) * XHS + 256 + mt * 16 + quad * 4] = p;
            }
        }

        // ---- acc init with bpost
        {
            u16x4 b0 = *(const u16x4*)(P.cbias + node * 2048 + 1024 + m * 256 + mt0 * 16 + quad * 4);
            u16x4 b1 = *(const u16x4*)(P.cbias + node * 2048 + 1024 + m * 256 + mt1 * 16 + quad * 4);
            f4v f0, f1;
#pragma unroll
            for (int r = 0; r < 4; r++) { f0[r] = bf2f(b0[r]); f1[r] = bf2f(b1[r]); }
#pragma unroll
            for (int nt = 0; nt < NT; nt++) { acc0[nt] = f0; acc1[nt] = f1; }
        }

        // ---- fused K-loop (barrier inside gemm_run, after prefetch issue)
        if (node == 0) gemm_run(IC<8>{},  P.rW01 + m * 8 * 8192, 8);
        else {
            const u16* WB = (node == 1 ? P.rWp1 : (node == 2 ? P.rWp2 : P.rWp3)) + m * 16 * 8192;
            gemm_run(IC<16>{}, WB, 0);
        }
        __syncthreads();                       // all xh reads of this node done

        // ---- relu + write hq^T -> xh[.,0..255]
#pragma unroll
        for (int ci = 0; ci < 2; ci++) {
            int mt = mt0 + ci;
#pragma unroll
            for (int nt = 0; nt < NT; nt++) {
                f4v a = ci ? acc1[nt] : acc0[nt];
                s4v p;
#pragma unroll
                for (int r = 0; r < 4; r++) { float v = a[r] > 0.f ? a[r] : 0.f; p[r] = (short)f2bf(v); }
                *(s4v*)&xh[(nt * 16 + l16) * XHS + mt * 16 + quad * 4] = p;
            }
        }
    }
    __syncthreads();

    // ---- final: out^T = Wfin^T @ x3^T + bfin (waves 0..NT-1)
    if (w < NT) {
        int m3 = (key >> 6) & 3;
        f4v c;
#pragma unroll
        for (int r = 0; r < 4; r++)
            c[r] = (quad < 2) ? bf2f(P.cbias[8192 + m3 * 8 + quad * 4 + r]) : 0.f;
#pragma unroll
        for (int s = 0; s < 8; s++) {
            s8v A = ld8(P.rFin + m3 * 4096 + s * 512 + lane * 8);
            s8v B = ld8(&xh[(w * 16 + l16) * XHS + s * 32 + quad * 8]);
            c = MFMA16(A, B, c);
        }
        int bidx = w * 16 + l16;
        if (quad < 2 && bidx < cntIn) {
            int row = rowids[bidx];
            if (flag) {
                s4v p;
#pragma unroll
                for (int r = 0; r < 4; r++) p[r] = (short)f2bf(c[r]);
                *(s4v*)((u16*)outp + row * 8 + quad * 4) = p;
            } else {
                *(f4v*)((float*)outp + row * 8 + quad * 4) = c;
            }
        }
    }
}

// ---------------------------------------------------------------------------
extern "C" void kernel_launch(void* const* d_in, const int* in_sizes, int n_in,
                              void* d_out, int out_size, void* d_ws, size_t ws_size,
                              hipStream_t stream)
{
    (void)in_sizes; (void)n_in; (void)out_size;
    const void* input  = d_in[0];
    const void* W00    = d_in[1];
    const void* b00    = d_in[2];
    const void* W01    = d_in[3];
    const void* b01    = d_in[4];
    const void* Wpre1  = d_in[5];
    const void* bpre1  = d_in[6];
    const void* Wpost1 = d_in[7];
    const void* bpost1 = d_in[8];
    const void* Wpre2  = d_in[9];
    const void* bpre2  = d_in[10];
    const void* Wpost2 = d_in[11];
    const void* bpost2 = d_in[12];
    const void* Wpre3  = d_in[13];
    const void* bpre3  = d_in[14];
    const void* Wpost3 = d_in[15];
    const void* bpost3 = d_in[16];
    const void* Wfin   = d_in[17];
    const void* bfin   = d_in[18];

    char* base = (char*)d_ws;
    size_t off = 0;
    auto alloc = [&](size_t bytes) -> char* {
        char* p = base + off;
        off += (bytes + 255) & ~(size_t)255;
        return p;
    };
    int*  hist      = (int*)alloc(128 * 256 * 4);
    u16*  keyloc    = (u16*)alloc(NB * 2);
    u16*  cbias    = (u16*)alloc(8224 * 2);
    u16*  rPre     = (u16*)alloc(131072 * 2);
    u16*  rW01     = (u16*)alloc(262144 * 2);
    u16*  rWp1     = (u16*)alloc(524288 * 2);
    u16*  rWp2     = (u16*)alloc(524288 * 2);
    u16*  rWp3     = (u16*)alloc(524288 * 2);
    u16*  rFin     = (u16*)alloc(16384 * 2);
    if (off > ws_size) return;

    RepArgs R;
    R.W01 = W01; R.Wp[0] = Wpost1; R.Wp[1] = Wpost2; R.Wp[2] = Wpost3;
    R.pre[0] = W00; R.pre[1] = Wpre1; R.pre[2] = Wpre2; R.pre[3] = Wpre3;
    R.fin = Wfin;
    R.bias[0] = b00;   R.bias[1] = b01;
    R.bias[2] = bpre1; R.bias[3] = bpost1;
    R.bias[4] = bpre2; R.bias[5] = bpost2;
    R.bias[6] = bpre3; R.bias[7] = bpost3;
    R.bias[8] = bfin;
    R.rPre = rPre; R.rW01 = rW01;
    R.rWp[0] = rWp1; R.rWp[1] = rWp2; R.rWp[2] = rWp3;
    R.rFin = rFin; R.cbias = cbias;

    prepA_kernel<<<373, 256, 0, stream>>>(input, hist, keyloc, R);

    MainP P;
    P.rPre = rPre; P.rW01 = rW01; P.rWp1 = rWp1; P.rWp2 = rWp2; P.rWp3 = rWp3;
    P.rFin = rFin; P.cbias = cbias;
    main_kernel<<<MAXTILE, 512, 0, stream>>>(input, hist, keyloc, P, d_out);
}

// Round 2
// 225.661 us; speedup vs baseline: 1.0114x; 1.0114x over previous
//
#include <hip/hip_runtime.h>

#define NB 32768
#define MAXTILE 768
#define ROWS 64
#define NT 4
#define XHS 536            // xh stride in u16: 268 dw ≡ 12 mod 32 → phase-minimal LDS access

typedef short s8v __attribute__((ext_vector_type(8)));   // 8 x bf16 bits (4 VGPR)
typedef short s4v __attribute__((ext_vector_type(4)));
typedef float f4v __attribute__((ext_vector_type(4)));
typedef unsigned short u16;
typedef unsigned short u16x4 __attribute__((ext_vector_type(4)));
typedef unsigned int u32;
typedef unsigned char u8;

__device__ __forceinline__ float bf2f(u16 u) { return __uint_as_float(((u32)u) << 16); }
__device__ __forceinline__ u16 f2bf(float f) {
    u32 x = __float_as_uint(f);
    x += 0x7FFFu + ((x >> 16) & 1u);   // RNE
    return (u16)(x >> 16);
}
__device__ __forceinline__ s8v ld8(const u16* p) { return *reinterpret_cast<const s8v*>(p); }

#define MFMA16(a, b, c) __builtin_amdgcn_mfma_f32_16x16x32_bf16((a), (b), (c), 0, 0, 0)

template <int N> struct IC { static constexpr int v = N; };

// dtype probe, done locally per block (wave 0 ballot -> LDS). bf16=1, f32=0.
__device__ __forceinline__ void detect_flag(const void* input, int tid, int* shflag)
{
    if (tid < 64) {
        u32 w = ((const u32*)input)[tid];
        u32 h0 = w & 0xFFFFu;
        u32 e0 = (h0 >> 7) & 0xFFu;
        bool plaus = (h0 == 0u) || (e0 >= 96u && e0 <= 143u);
        unsigned long long m = __ballot(plaus);
        if (tid == 0) *shflag = (__popcll(m) >= 48) ? 1 : 0;
    }
}

// ---------------------------------------------------------------------------
// dispatch A: blocks [0,128): per-block key count (LDS) -> one global
// atomicAdd per (block,key) reserves a contiguous rank range in gcnt ->
// rows scattered straight into perm2[key*512 + rank]. Rank order within a
// key is nondeterministic, which is fine: outputs scatter by absolute row.
// gcnt must be zeroed by a preceding hipMemsetAsync.
// blocks [128,373): weight repack to A-frag layout + bias conversion.
// ---------------------------------------------------------------------------
struct RepArgs {
    const void* W01; const void* Wp[3]; const void* pre[4]; const void* fin;
    const void* bias[9];
    u16 *rPre, *rW01, *rWp[3], *rFin, *cbias;
};

__global__ __launch_bounds__(256) void prepA_kernel(const void* __restrict__ inputv,
                                                    int* __restrict__ gcnt,       // [256]
                                                    int* __restrict__ perm2,      // [256][512]
                                                    RepArgs R)
{
    __shared__ int lcnt[256];
    __shared__ int sBase[256];
    __shared__ u16 T[8192];
    __shared__ int shmisc;
    int tid = threadIdx.x;
    int b = blockIdx.x;
    detect_flag(inputv, tid, &shmisc);
    __syncthreads();
    int flag = shmisc;

    if (b < 128) {
        lcnt[tid] = 0;
        __syncthreads();
        int row = (b << 8) + tid;
        const u32* in32 = (const u32*)inputv;
        const u16* in16 = (const u16*)inputv;
        int key = 0;
        if (flag) {
#pragma unroll
            for (int j = 0; j < 4; j++) {
                u16x4 v = *(const u16x4*)(in16 + row * 144 + 128 + j * 4);
                int m = v[1] ? 1 : (v[2] ? 2 : (v[3] ? 3 : 0));
                key |= m << (j << 1);
            }
        } else {
#pragma unroll
            for (int j = 0; j < 4; j++) {
                const u32* p = in32 + row * 144 + 128 + j * 4;
                u32 v1 = p[1], v2 = p[2], v3 = p[3];
                int m = v1 ? 1 : (v2 ? 2 : (v3 ? 3 : 0));
                key |= m << (j << 1);
            }
        }
        int loc = atomicAdd(&lcnt[key], 1);
        __syncthreads();
        int c = lcnt[tid];
        sBase[tid] = c ? atomicAdd(&gcnt[tid], c) : 0;   // device-scope reservation
        __syncthreads();
        int slot = sBase[key] + loc;
        if (slot < 512) perm2[(key << 9) + slot] = row;  // cap guard (stat. impossible)
        return;
    }

    // ---- repack path
    int rb = b - 128;
    const void* src = nullptr; u16* dst = nullptr; int K = 0, k0 = 0, mrow = 0;
    if (rb < 32) {
        int m = rb >> 3, s = rb & 7;
        src = R.W01; dst = R.rW01 + (m * 8 + s) * 8192; K = 256; k0 = s * 32; mrow = m;
    } else if (rb < 224) {
        int idx = rb - 32, mat = idx >> 6, r = idx & 63, m = r >> 4, s = r & 15;
        src = R.Wp[mat]; dst = R.rWp[mat] + (m * 16 + s) * 8192; K = 512; k0 = s * 32; mrow = m;
    } else if (rb < 240) {
        int idx = rb - 224, mat = idx >> 2, m = idx & 3;
        src = R.pre[mat]; dst = R.rPre + (mat * 4 + m) * 8192; K = 32; k0 = 0; mrow = m;
    } else if (rb < 244) {
        int m = rb - 240;   // Wfin [m][256][8] -> [m][s8][lane][8], rows l16>=8 zero
        const u16* s16 = (const u16*)R.fin;
        const float* s32 = (const float*)R.fin;
        for (int i = tid; i < 2048; i += 256) {
            int si = (m * 256 + (i >> 3)) * 8 + (i & 7);
            T[i] = flag ? s16[si] : f2bf(s32[si]);
        }
        __syncthreads();
        u16* d = R.rFin + m * 4096;
        for (int i = tid; i < 4096; i += 256) {
            int s = i >> 9, lane = (i >> 3) & 63, j = i & 7;
            int q = lane >> 4, l16 = lane & 15;
            int k = s * 32 + q * 8 + j;
            d[i] = (l16 < 8) ? T[k * 8 + l16] : (u16)0;
        }
        return;
    } else {
        const int sz[9] = {1024,1024,1024,1024,1024,1024,1024,1024,32};
        const int of[9] = {0,1024,2048,3072,4096,5120,6144,7168,8192};
        for (int i = tid; i < 8224; i += 256) {
            int t = i, e = 0;
            while (t >= sz[e]) { t -= sz[e]; e++; }
            R.cbias[of[e] + t] = flag ? ((const u16*)R.bias[e])[t]
                                      : f2bf(((const float*)R.bias[e])[t]);
        }
        return;
    }
    const u16* s16 = (const u16*)src;
    const float* s32 = (const float*)src;
    for (int i = tid; i < 8192; i += 256) {
        int k = i >> 8, n = i & 255;
        int srcIdx = (mrow * K + k0 + k) * 256 + n;
        T[i] = flag ? s16[srcIdx] : f2bf(s32[srcIdx]);
    }
    __syncthreads();
    for (int i = tid; i < 8192; i += 256) {
        int mt = i >> 9, lane = (i >> 3) & 63, j = i & 7;
        int k = ((lane >> 4) << 3) + j, n = (mt << 4) + (lane & 15);
        dst[i] = T[(k << 8) + n];
    }
}

// ---------------------------------------------------------------------------
// main: one block = 64 rows through the whole net (T-formulation).
// 8 waves; wave w: m-tiles {2w,2w+1} x 4 n-tiles. Fused K=512 gemm, depth-4
// weight prefetch issued before the barrier. XCD-aware tile swizzle.
//
// Cheap prologue (~1-2us): load gcnt[256] (one value/thread), one 8-step
// tile-count scan finds (key,tau,cnt) for this block, then 64 coalesced
// perm2 reads give the row ids. No hist scan, no keyloc sweep.
//
// T5: setprio(1) around the K-loop. T14: next node's feature-row loads are
// issued inside gemm_run (register-destined -> legally in flight across the
// barrier), hiding the scattered 64-line gather under the MFMA phase.
// ---------------------------------------------------------------------------
struct MainP { const u16 *rPre, *rW01, *rWp1, *rWp2, *rWp3, *rFin, *cbias; };

__global__ __launch_bounds__(512, 4) void main_kernel(
    const void* __restrict__ inRaw,
    const int* __restrict__ gcnt, const int* __restrict__ perm2,
    MainP P, void* __restrict__ outp)
{
    __shared__ __align__(16) u16 xh[ROWS * XHS];
    __shared__ int rowids[ROWS];
    __shared__ int shflag;
    __shared__ int sScan[256];
    __shared__ int sMeta[3];   // key, tau, tot

    int tid = threadIdx.x;
    int lane = tid & 63, w = tid >> 6, quad = lane >> 4, l16 = lane & 15;

    int b = blockIdx.x;
    int t = ((b & 7) * (MAXTILE / 8)) + (b >> 3);   // XCD-contiguous tile runs

    detect_flag(inRaw, tid, &shflag);

    // ---- prologue: tile-count scan over per-key totals
    int myTiles = 0, myTot = 0;
    if (tid < 256) {
        myTot = gcnt[tid];
        myTiles = (myTot + ROWS - 1) >> 6;
        sScan[tid] = myTiles;
    }
    __syncthreads();
    for (int off = 1; off < 256; off <<= 1) {
        int v = (tid >= off && tid < 256) ? sScan[tid - off] : 0;
        __syncthreads();
        if (tid < 256) sScan[tid] += v;
        __syncthreads();
    }
    if (tid < 256 && myTiles) {
        int tb = sScan[tid] - myTiles;
        if (t >= tb && t < sScan[tid]) {   // exactly one thread matches
            sMeta[0] = tid;                // key
            sMeta[1] = t - tb;             // tau
            sMeta[2] = myTot;              // tot
        }
    }
    __syncthreads();
    int ttot = sScan[255];
    if (t >= ttot) return;                 // block-uniform exit
    int key = sMeta[0], tau = sMeta[1], tot = sMeta[2];
    int cntIn = tot - tau * ROWS; if (cntIn > ROWS) cntIn = ROWS;
    if (tid < ROWS) {
        int g = tid < cntIn ? tid : cntIn - 1;   // clamp partial tile (dups benign)
        rowids[tid] = perm2[(key << 9) + tau * ROWS + g];
    }
    __syncthreads();

    int flag = shflag;
    int rows_[NT];
#pragma unroll
    for (int nt = 0; nt < NT; nt++) rows_[nt] = rowids[nt * 16 + l16];

    const u16* in16 = (const u16*)inRaw;
    const float* in32 = (const float*)inRaw;
    int mt0 = w << 1, mt1 = mt0 + 1;

    f4v acc0[NT], acc1[NT];

    // feature-row prefetch state (raw bits; converted at use)
    f4v raw0[NT], raw1[NT];
    auto issue_fb = [&](int node) {
#pragma unroll
        for (int nt = 0; nt < NT; nt++) {
            int off = rows_[nt] * 144 + (node << 5) + (quad << 3);
            if (flag) {
                raw0[nt] = *(const f4v*)(in16 + off);     // 16B of bf16 bits
            } else {
                raw0[nt] = *(const f4v*)(in32 + off);
                raw1[nt] = *(const f4v*)(in32 + off + 4);
            }
        }
    };
    auto conv_fb = [&](int nt) -> s8v {
        if (flag) return *(s8v*)&raw0[nt];
        s8v r;
#pragma unroll
        for (int j = 0; j < 4; j++) {
            r[j]     = (short)f2bf(raw0[nt][j]);
            r[4 + j] = (short)f2bf(raw1[nt][j]);
        }
        return r;
    };

    // N-slice fused GEMM: A prefetch window depth 4 + next-node feature loads
    // issued BEFORE the hp-visibility barrier (neither depends on xh).
    auto gemm_run = [&](auto nc, const u16* Ab, int ks0, int nextNode) {
        constexpr int N = decltype(nc)::v;
        constexpr int D = 4;
        const u16* base0 = Ab + mt0 * 512 + lane * 8;
        const u16* base1 = Ab + mt1 * 512 + lane * 8;
        s8v A0[D], A1[D];
#pragma unroll
        for (int d = 0; d < D && d < N; d++) {
            A0[d] = ld8(base0 + d * 8192);
            A1[d] = ld8(base1 + d * 8192);
        }
        if (nextNode >= 0) issue_fb(nextNode);   // in flight across the barrier
        __syncthreads();                         // hp/hq now visible
        __builtin_amdgcn_s_setprio(1);
#pragma unroll
        for (int s = 0; s < N; s++) {
            s8v c0 = A0[s % D], c1 = A1[s % D];
            if (s + D < N) {
                A0[s % D] = ld8(base0 + (s + D) * 8192);
                A1[s % D] = ld8(base1 + (s + D) * 8192);
            }
#pragma unroll
            for (int nt = 0; nt < NT; nt++) {
                s8v B = ld8(&xh[(nt * 16 + l16) * XHS + (ks0 + s) * 32 + quad * 8]);
                acc0[nt] = MFMA16(c0, B, acc0[nt]);
                acc1[nt] = MFMA16(c1, B, acc1[nt]);
            }
        }
        __builtin_amdgcn_s_setprio(0);
    };

    issue_fb(0);
    for (int node = 0; node < 4; node++) {
        int m = (key >> (node << 1)) & 3;

        // ---- hp^T = relu(Wpre^T @ feats^T + bpre) -> xh[.,256..511]
        s8v fb[NT];
#pragma unroll
        for (int nt = 0; nt < NT; nt++) fb[nt] = conv_fb(nt);

        const u16* preB = P.rPre + ((node << 2) + m) * 8192;
#pragma unroll
        for (int ci = 0; ci < 2; ci++) {
            int mt = mt0 + ci;
            s8v a = ld8(preB + mt * 512 + lane * 8);
            u16x4 bv = *(const u16x4*)(P.cbias + node * 2048 + m * 256 + mt * 16 + quad * 4);
            f4v bias;
#pragma unroll
            for (int r = 0; r < 4; r++) bias[r] = bf2f(bv[r]);
#pragma unroll
            for (int nt = 0; nt < NT; nt++) {
                f4v c = MFMA16(a, fb[nt], bias);
                s4v p;
#pragma unroll
                for (int r = 0; r < 4; r++) { float v = c[r] > 0.f ? c[r] : 0.f; p[r] = (short)f2bf(v); }
                *(s4v*)&xh[(nt * 16 + l16) * XHS + 256 + mt * 16 + quad * 4] = p;
            }
        }

        // ---- acc init with bpost
        {
            u16x4 b0 = *(const u16x4*)(P.cbias + node * 2048 + 1024 + m * 256 + mt0 * 16 + quad * 4);
            u16x4 b1 = *(const u16x4*)(P.cbias + node * 2048 + 1024 + m * 256 + mt1 * 16 + quad * 4);
            f4v f0, f1;
#pragma unroll
            for (int r = 0; r < 4; r++) { f0[r] = bf2f(b0[r]); f1[r] = bf2f(b1[r]); }
#pragma unroll
            for (int nt = 0; nt < NT; nt++) { acc0[nt] = f0; acc1[nt] = f1; }
        }

        // ---- fused K-loop (barrier inside gemm_run, after prefetch issue)
        if (node == 0) gemm_run(IC<8>{},  P.rW01 + m * 8 * 8192, 8, 1);
        else {
            const u16* WB = (node == 1 ? P.rWp1 : (node == 2 ? P.rWp2 : P.rWp3)) + m * 16 * 8192;
            gemm_run(IC<16>{}, WB, 0, node < 3 ? node + 1 : -1);
        }
        __syncthreads();                       // all xh reads of this node done

        // ---- relu + write hq^T -> xh[.,0..255]
#pragma unroll
        for (int ci = 0; ci < 2; ci++) {
            int mt = mt0 + ci;
#pragma unroll
            for (int nt = 0; nt < NT; nt++) {
                f4v a = ci ? acc1[nt] : acc0[nt];
                s4v p;
#pragma unroll
                for (int r = 0; r < 4; r++) { float v = a[r] > 0.f ? a[r] : 0.f; p[r] = (short)f2bf(v); }
                *(s4v*)&xh[(nt * 16 + l16) * XHS + mt * 16 + quad * 4] = p;
            }
        }
    }
    __syncthreads();

    // ---- final: out^T = Wfin^T @ x3^T + bfin (waves 0..NT-1)
    if (w < NT) {
        int m3 = (key >> 6) & 3;
        f4v c;
#pragma unroll
        for (int r = 0; r < 4; r++)
            c[r] = (quad < 2) ? bf2f(P.cbias[8192 + m3 * 8 + quad * 4 + r]) : 0.f;
#pragma unroll
        for (int s = 0; s < 8; s++) {
            s8v A = ld8(P.rFin + m3 * 4096 + s * 512 + lane * 8);
            s8v B = ld8(&xh[(w * 16 + l16) * XHS + s * 32 + quad * 8]);
            c = MFMA16(A, B, c);
        }
        int bidx = w * 16 + l16;
        if (quad < 2 && bidx < cntIn) {
            int row = rowids[bidx];
            if (flag) {
                s4v p;
#pragma unroll
                for (int r = 0; r < 4; r++) p[r] = (short)f2bf(c[r]);
                *(s4v*)((u16*)outp + row * 8 + quad * 4) = p;
            } else {
                *(f4v*)((float*)outp + row * 8 + quad * 4) = c;
            }
        }
    }
}

// ---------------------------------------------------------------------------
extern "C" void kernel_launch(void* const* d_in, const int* in_sizes, int n_in,
                              void* d_out, int out_size, void* d_ws, size_t ws_size,
                              hipStream_t stream)
{
    (void)in_sizes; (void)n_in; (void)out_size;
    const void* input  = d_in[0];
    const void* W00    = d_in[1];
    const void* b00    = d_in[2];
    const void* W01    = d_in[3];
    const void* b01    = d_in[4];
    const void* Wpre1  = d_in[5];
    const void* bpre1  = d_in[6];
    const void* Wpost1 = d_in[7];
    const void* bpost1 = d_in[8];
    const void* Wpre2  = d_in[9];
    const void* bpre2  = d_in[10];
    const void* Wpost2 = d_in[11];
    const void* bpost2 = d_in[12];
    const void* Wpre3  = d_in[13];
    const void* bpre3  = d_in[14];
    const void* Wpost3 = d_in[15];
    const void* bpost3 = d_in[16];
    const void* Wfin   = d_in[17];
    const void* bfin   = d_in[18];

    char* base = (char*)d_ws;
    size_t off = 0;
    auto alloc = [&](size_t bytes) -> char* {
        char* p = base + off;
        off += (bytes + 255) & ~(size_t)255;
        return p;
    };
    int*  gcnt      = (int*)alloc(256 * 4);
    int*  perm2     = (int*)alloc(256 * 512 * 4);
    u16*  cbias    = (u16*)alloc(8224 * 2);
    u16*  rPre     = (u16*)alloc(131072 * 2);
    u16*  rW01     = (u16*)alloc(262144 * 2);
    u16*  rWp1     = (u16*)alloc(524288 * 2);
    u16*  rWp2     = (u16*)alloc(524288 * 2);
    u16*  rWp3     = (u16*)alloc(524288 * 2);
    u16*  rFin     = (u16*)alloc(16384 * 2);
    if (off > ws_size) return;

    RepArgs R;
    R.W01 = W01; R.Wp[0] = Wpost1; R.Wp[1] = Wpost2; R.Wp[2] = Wpost3;
    R.pre[0] = W00; R.pre[1] = Wpre1; R.pre[2] = Wpre2; R.pre[3] = Wpre3;
    R.fin = Wfin;
    R.bias[0] = b00;   R.bias[1] = b01;
    R.bias[2] = bpre1; R.bias[3] = bpost1;
    R.bias[4] = bpre2; R.bias[5] = bpost2;
    R.bias[6] = bpre3; R.bias[7] = bpost3;
    R.bias[8] = bfin;
    R.rPre = rPre; R.rW01 = rW01;
    R.rWp[0] = rWp1; R.rWp[1] = rWp2; R.rWp[2] = rWp3;
    R.rFin = rFin; R.cbias = cbias;

    hipMemsetAsync(gcnt, 0, 256 * 4, stream);
    prepA_kernel<<<373, 256, 0, stream>>>(input, gcnt, perm2, R);

    MainP P;
    P.rPre = rPre; P.rW01 = rW01; P.rWp1 = rWp1; P.rWp2 = rWp2; P.rWp3 = rWp3;
    P.rFin = rFin; P.cbias = cbias;
    main_kernel<<<MAXTILE, 512, 0, stream>>>(input, gcnt, perm2, P, d_out);
}

// Round 3
// 191.299 us; speedup vs baseline: 1.1931x; 1.1796x over previous
//
#include <hip/hip_runtime.h>

#define NB 32768
#define MAXTILE 768
#define ROWS 64
#define NT 4
#define XHS 536            // xh stride in u16: 268 dw ≡ 12 mod 32 → phase-minimal LDS access

typedef short s8v __attribute__((ext_vector_type(8)));   // 8 x bf16 bits (4 VGPR)
typedef short s4v __attribute__((ext_vector_type(4)));
typedef float f4v __attribute__((ext_vector_type(4)));
typedef unsigned short u16;
typedef unsigned short u16x4 __attribute__((ext_vector_type(4)));
typedef unsigned int u32;
typedef unsigned char u8;

__device__ __forceinline__ float bf2f(u16 u) { return __uint_as_float(((u32)u) << 16); }
__device__ __forceinline__ u16 f2bf(float f) {
    u32 x = __float_as_uint(f);
    x += 0x7FFFu + ((x >> 16) & 1u);   // RNE
    return (u16)(x >> 16);
}
__device__ __forceinline__ s8v ld8(const u16* p) { return *reinterpret_cast<const s8v*>(p); }

#define MFMA16(a, b, c) __builtin_amdgcn_mfma_f32_16x16x32_bf16((a), (b), (c), 0, 0, 0)

template <int N> struct IC { static constexpr int v = N; };

// dtype probe, done locally per block (wave 0 ballot -> LDS). bf16=1, f32=0.
__device__ __forceinline__ void detect_flag(const void* input, int tid, int* shflag)
{
    if (tid < 64) {
        u32 w = ((const u32*)input)[tid];
        u32 h0 = w & 0xFFFFu;
        u32 e0 = (h0 >> 7) & 0xFFu;
        bool plaus = (h0 == 0u) || (e0 >= 96u && e0 <= 143u);
        unsigned long long m = __ballot(plaus);
        if (tid == 0) *shflag = (__popcll(m) >= 48) ? 1 : 0;
    }
}

// ---------------------------------------------------------------------------
// dispatch A: blocks [0,128): per-block key count (LDS) -> one global
// atomicAdd per (block,key) reserves a contiguous rank range in gcnt ->
// rows scattered straight into perm2[key*512 + rank]. Rank order within a
// key is nondeterministic, which is fine: outputs scatter by absolute row.
// gcnt must be zeroed by a preceding hipMemsetAsync.
// blocks [128,373): weight repack to A-frag layout + bias conversion.
// ---------------------------------------------------------------------------
struct RepArgs {
    const void* W01; const void* Wp[3]; const void* pre[4]; const void* fin;
    const void* bias[9];
    u16 *rPre, *rW01, *rWp[3], *rFin, *cbias;
};

__global__ __launch_bounds__(256) void prepA_kernel(const void* __restrict__ inputv,
                                                    int* __restrict__ gcnt,       // [256]
                                                    int* __restrict__ perm2,      // [256][512]
                                                    RepArgs R)
{
    __shared__ int lcnt[256];
    __shared__ int sBase[256];
    __shared__ u16 T[8192];
    __shared__ int shmisc;
    int tid = threadIdx.x;
    int b = blockIdx.x;
    detect_flag(inputv, tid, &shmisc);
    __syncthreads();
    int flag = shmisc;

    if (b < 128) {
        lcnt[tid] = 0;
        __syncthreads();
        int row = (b << 8) + tid;
        const u32* in32 = (const u32*)inputv;
        const u16* in16 = (const u16*)inputv;
        int key = 0;
        if (flag) {
#pragma unroll
            for (int j = 0; j < 4; j++) {
                u16x4 v = *(const u16x4*)(in16 + row * 144 + 128 + j * 4);
                int m = v[1] ? 1 : (v[2] ? 2 : (v[3] ? 3 : 0));
                key |= m << (j << 1);
            }
        } else {
#pragma unroll
            for (int j = 0; j < 4; j++) {
                const u32* p = in32 + row * 144 + 128 + j * 4;
                u32 v1 = p[1], v2 = p[2], v3 = p[3];
                int m = v1 ? 1 : (v2 ? 2 : (v3 ? 3 : 0));
                key |= m << (j << 1);
            }
        }
        int loc = atomicAdd(&lcnt[key], 1);
        __syncthreads();
        int c = lcnt[tid];
        sBase[tid] = c ? atomicAdd(&gcnt[tid], c) : 0;   // device-scope reservation
        __syncthreads();
        int slot = sBase[key] + loc;
        if (slot < 512) perm2[(key << 9) + slot] = row;  // cap guard (stat. impossible)
        return;
    }

    // ---- repack path
    int rb = b - 128;
    const void* src = nullptr; u16* dst = nullptr; int K = 0, k0 = 0, mrow = 0;
    if (rb < 32) {
        int m = rb >> 3, s = rb & 7;
        src = R.W01; dst = R.rW01 + (m * 8 + s) * 8192; K = 256; k0 = s * 32; mrow = m;
    } else if (rb < 224) {
        int idx = rb - 32, mat = idx >> 6, r = idx & 63, m = r >> 4, s = r & 15;
        src = R.Wp[mat]; dst = R.rWp[mat] + (m * 16 + s) * 8192; K = 512; k0 = s * 32; mrow = m;
    } else if (rb < 240) {
        int idx = rb - 224, mat = idx >> 2, m = idx & 3;
        src = R.pre[mat]; dst = R.rPre + (mat * 4 + m) * 8192; K = 32; k0 = 0; mrow = m;
    } else if (rb < 244) {
        int m = rb - 240;   // Wfin [m][256][8] -> [m][s8][lane][8], rows l16>=8 zero
        const u16* s16 = (const u16*)R.fin;
        const float* s32 = (const float*)R.fin;
        for (int i = tid; i < 2048; i += 256) {
            int si = (m * 256 + (i >> 3)) * 8 + (i & 7);
            T[i] = flag ? s16[si] : f2bf(s32[si]);
        }
        __syncthreads();
        u16* d = R.rFin + m * 4096;
        for (int i = tid; i < 4096; i += 256) {
            int s = i >> 9, lane = (i >> 3) & 63, j = i & 7;
            int q = lane >> 4, l16 = lane & 15;
            int k = s * 32 + q * 8 + j;
            d[i] = (l16 < 8) ? T[k * 8 + l16] : (u16)0;
        }
        return;
    } else {
        const int sz[9] = {1024,1024,1024,1024,1024,1024,1024,1024,32};
        const int of[9] = {0,1024,2048,3072,4096,5120,6144,7168,8192};
        for (int i = tid; i < 8224; i += 256) {
            int t = i, e = 0;
            while (t >= sz[e]) { t -= sz[e]; e++; }
            R.cbias[of[e] + t] = flag ? ((const u16*)R.bias[e])[t]
                                      : f2bf(((const float*)R.bias[e])[t]);
        }
        return;
    }
    const u16* s16 = (const u16*)src;
    const float* s32 = (const float*)src;
    for (int i = tid; i < 8192; i += 256) {
        int k = i >> 8, n = i & 255;
        int srcIdx = (mrow * K + k0 + k) * 256 + n;
        T[i] = flag ? s16[srcIdx] : f2bf(s32[srcIdx]);
    }
    __syncthreads();
    for (int i = tid; i < 8192; i += 256) {
        int mt = i >> 9, lane = (i >> 3) & 63, j = i & 7;
        int k = ((lane >> 4) << 3) + j, n = (mt << 4) + (lane & 15);
        dst[i] = T[(k << 8) + n];
    }
}

// ---------------------------------------------------------------------------
// main: one block = 64 rows through the whole net (T-formulation).
// 8 waves; wave w: m-tiles {2w,2w+1} x 4 n-tiles. Fused K=512 gemm, depth-6
// weight prefetch issued before the barrier. XCD-aware tile swizzle.
//
// Prologue (barrier-free scan): wave 0 loads gcnt[256] (4 keys/lane, int4),
// 6-step __shfl_up scan of tile counts -> (key, tau, tot) for this block,
// then 64 coalesced perm2 reads give the row ids. Two barriers total.
//
// Feature gather is SYNCHRONOUS per node (consumed immediately — r2's
// cross-K-loop register prefetch spilled to scratch: WRITE_SIZE 1->68MB).
// ---------------------------------------------------------------------------
struct MainP { const u16 *rPre, *rW01, *rWp1, *rWp2, *rWp3, *rFin, *cbias; };

__global__ __launch_bounds__(512, 4) void main_kernel(
    const void* __restrict__ inRaw,
    const int* __restrict__ gcnt, const int* __restrict__ perm2,
    MainP P, void* __restrict__ outp)
{
    __shared__ __align__(16) u16 xh[ROWS * XHS];
    __shared__ int rowids[ROWS];
    __shared__ int shflag;
    __shared__ int sMeta[4];   // key, tau, tot, ttot

    int tid = threadIdx.x;
    int lane = tid & 63, w = tid >> 6, quad = lane >> 4, l16 = lane & 15;

    int b = blockIdx.x;
    int t = ((b & 7) * (MAXTILE / 8)) + (b >> 3);   // XCD-contiguous tile runs

    detect_flag(inRaw, tid, &shflag);

    // ---- prologue: wave-0 shuffle scan over per-key tile counts
    if (tid < 64) {
        int4 g = *(const int4*)(gcnt + tid * 4);
        int tot4[4] = {g.x, g.y, g.z, g.w};
        int tiles4[4], lsum = 0;
#pragma unroll
        for (int j = 0; j < 4; j++) { tiles4[j] = (tot4[j] + 63) >> 6; lsum += tiles4[j]; }
        int pre = lsum;
#pragma unroll
        for (int off = 1; off < 64; off <<= 1) {
            int v = __shfl_up(pre, off, 64);
            if (tid >= off) pre += v;
        }
        int run = pre - lsum;            // exclusive base for this lane's 4 keys
#pragma unroll
        for (int j = 0; j < 4; j++) {
            if (t >= run && t < run + tiles4[j]) {   // exactly one (lane,j) matches
                sMeta[0] = tid * 4 + j;  // key
                sMeta[1] = t - run;      // tau
                sMeta[2] = tot4[j];      // tot
            }
            run += tiles4[j];
        }
        if (tid == 63) sMeta[3] = pre;   // total tiles
    }
    __syncthreads();
    if (t >= sMeta[3]) return;           // block-uniform exit
    int key = sMeta[0], tau = sMeta[1], tot = sMeta[2];
    int cntIn = tot - tau * ROWS; if (cntIn > ROWS) cntIn = ROWS;
    if (tid < ROWS) {
        int g = tid < cntIn ? tid : cntIn - 1;   // clamp partial tile (dups benign)
        rowids[tid] = perm2[(key << 9) + tau * ROWS + g];
    }
    __syncthreads();

    int flag = shflag;
    int rows_[NT];
#pragma unroll
    for (int nt = 0; nt < NT; nt++) rows_[nt] = rowids[nt * 16 + l16];

    const u16* in16 = (const u16*)inRaw;
    const float* in32 = (const float*)inRaw;
    int mt0 = w << 1, mt1 = mt0 + 1;

    f4v acc0[NT], acc1[NT];

    // N-slice fused GEMM: A prefetch window depth 6 (4 for the short node-0
    // loop), first loads issued BEFORE the hp-visibility barrier (A-frags
    // don't depend on xh).
    auto gemm_run = [&](auto nc, const u16* Ab, int ks0) {
        constexpr int N = decltype(nc)::v;
        constexpr int D = (N > 8) ? 6 : 4;
        const u16* base0 = Ab + mt0 * 512 + lane * 8;
        const u16* base1 = Ab + mt1 * 512 + lane * 8;
        s8v A0[D], A1[D];
#pragma unroll
        for (int d = 0; d < D && d < N; d++) {
            A0[d] = ld8(base0 + d * 8192);
            A1[d] = ld8(base1 + d * 8192);
        }
        __syncthreads();                     // hp/hq now visible; prefetch in flight
        __builtin_amdgcn_s_setprio(1);
#pragma unroll
        for (int s = 0; s < N; s++) {
            s8v c0 = A0[s % D], c1 = A1[s % D];
            if (s + D < N) {
                A0[s % D] = ld8(base0 + (s + D) * 8192);
                A1[s % D] = ld8(base1 + (s + D) * 8192);
            }
#pragma unroll
            for (int nt = 0; nt < NT; nt++) {
                s8v B = ld8(&xh[(nt * 16 + l16) * XHS + (ks0 + s) * 32 + quad * 8]);
                acc0[nt] = MFMA16(c0, B, acc0[nt]);
                acc1[nt] = MFMA16(c1, B, acc1[nt]);
            }
        }
        __builtin_amdgcn_s_setprio(0);
    };

    for (int node = 0; node < 4; node++) {
        int m = (key >> (node << 1)) & 3;

        // ---- feats B-frags: direct gather (consumed immediately, no spill)
        s8v fb[NT];
#pragma unroll
        for (int nt = 0; nt < NT; nt++) {
            int off = rows_[nt] * 144 + (node << 5) + (quad << 3);
            if (flag) fb[nt] = ld8(in16 + off);
            else {
                f4v f0 = *(const f4v*)(in32 + off);
                f4v f1 = *(const f4v*)(in32 + off + 4);
                s8v r;
#pragma unroll
                for (int j = 0; j < 4; j++) { r[j] = (short)f2bf(f0[j]); r[4 + j] = (short)f2bf(f1[j]); }
                fb[nt] = r;
            }
        }

        // ---- hp^T = relu(Wpre^T @ feats^T + bpre) -> xh[.,256..511]
        const u16* preB = P.rPre + ((node << 2) + m) * 8192;
#pragma unroll
        for (int ci = 0; ci < 2; ci++) {
            int mt = mt0 + ci;
            s8v a = ld8(preB + mt * 512 + lane * 8);
            u16x4 bv = *(const u16x4*)(P.cbias + node * 2048 + m * 256 + mt * 16 + quad * 4);
            f4v bias;
#pragma unroll
            for (int r = 0; r < 4; r++) bias[r] = bf2f(bv[r]);
#pragma unroll
            for (int nt = 0; nt < NT; nt++) {
                f4v c = MFMA16(a, fb[nt], bias);
                s4v p;
#pragma unroll
                for (int r = 0; r < 4; r++) { float v = c[r] > 0.f ? c[r] : 0.f; p[r] = (short)f2bf(v); }
                *(s4v*)&xh[(nt * 16 + l16) * XHS + 256 + mt * 16 + quad * 4] = p;
            }
        }

        // ---- acc init with bpost
        {
            u16x4 b0 = *(const u16x4*)(P.cbias + node * 2048 + 1024 + m * 256 + mt0 * 16 + quad * 4);
            u16x4 b1 = *(const u16x4*)(P.cbias + node * 2048 + 1024 + m * 256 + mt1 * 16 + quad * 4);
            f4v f0, f1;
#pragma unroll
            for (int r = 0; r < 4; r++) { f0[r] = bf2f(b0[r]); f1[r] = bf2f(b1[r]); }
#pragma unroll
            for (int nt = 0; nt < NT; nt++) { acc0[nt] = f0; acc1[nt] = f1; }
        }

        // ---- fused K-loop (barrier inside gemm_run, after prefetch issue)
        if (node == 0) gemm_run(IC<8>{},  P.rW01 + m * 8 * 8192, 8);
        else {
            const u16* WB = (node == 1 ? P.rWp1 : (node == 2 ? P.rWp2 : P.rWp3)) + m * 16 * 8192;
            gemm_run(IC<16>{}, WB, 0);
        }
        __syncthreads();                       // all xh reads of this node done

        // ---- relu + write hq^T -> xh[.,0..255]
#pragma unroll
        for (int ci = 0; ci < 2; ci++) {
            int mt = mt0 + ci;
#pragma unroll
            for (int nt = 0; nt < NT; nt++) {
                f4v a = ci ? acc1[nt] : acc0[nt];
                s4v p;
#pragma unroll
                for (int r = 0; r < 4; r++) { float v = a[r] > 0.f ? a[r] : 0.f; p[r] = (short)f2bf(v); }
                *(s4v*)&xh[(nt * 16 + l16) * XHS + mt * 16 + quad * 4] = p;
            }
        }
    }
    __syncthreads();

    // ---- final: out^T = Wfin^T @ x3^T + bfin (waves 0..NT-1)
    if (w < NT) {
        int m3 = (key >> 6) & 3;
        f4v c;
#pragma unroll
        for (int r = 0; r < 4; r++)
            c[r] = (quad < 2) ? bf2f(P.cbias[8192 + m3 * 8 + quad * 4 + r]) : 0.f;
#pragma unroll
        for (int s = 0; s < 8; s++) {
            s8v A = ld8(P.rFin + m3 * 4096 + s * 512 + lane * 8);
            s8v B = ld8(&xh[(w * 16 + l16) * XHS + s * 32 + quad * 8]);
            c = MFMA16(A, B, c);
        }
        int bidx = w * 16 + l16;
        if (quad < 2 && bidx < cntIn) {
            int row = rowids[bidx];
            if (flag) {
                s4v p;
#pragma unroll
                for (int r = 0; r < 4; r++) p[r] = (short)f2bf(c[r]);
                *(s4v*)((u16*)outp + row * 8 + quad * 4) = p;
            } else {
                *(f4v*)((float*)outp + row * 8 + quad * 4) = c;
            }
        }
    }
}

// ---------------------------------------------------------------------------
extern "C" void kernel_launch(void* const* d_in, const int* in_sizes, int n_in,
                              void* d_out, int out_size, void* d_ws, size_t ws_size,
                              hipStream_t stream)
{
    (void)in_sizes; (void)n_in; (void)out_size;
    const void* input  = d_in[0];
    const void* W00    = d_in[1];
    const void* b00    = d_in[2];
    const void* W01    = d_in[3];
    const void* b01    = d_in[4];
    const void* Wpre1  = d_in[5];
    const void* bpre1  = d_in[6];
    const void* Wpost1 = d_in[7];
    const void* bpost1 = d_in[8];
    const void* Wpre2  = d_in[9];
    const void* bpre2  = d_in[10];
    const void* Wpost2 = d_in[11];
    const void* bpost2 = d_in[12];
    const void* Wpre3  = d_in[13];
    const void* bpre3  = d_in[14];
    const void* Wpost3 = d_in[15];
    const void* bpost3 = d_in[16];
    const void* Wfin   = d_in[17];
    const void* bfin   = d_in[18];

    char* base = (char*)d_ws;
    size_t off = 0;
    auto alloc = [&](size_t bytes) -> char* {
        char* p = base + off;
        off += (bytes + 255) & ~(size_t)255;
        return p;
    };
    int*  gcnt      = (int*)alloc(256 * 4);
    int*  perm2     = (int*)alloc(256 * 512 * 4);
    u16*  cbias    = (u16*)alloc(8224 * 2);
    u16*  rPre     = (u16*)alloc(131072 * 2);
    u16*  rW01     = (u16*)alloc(262144 * 2);
    u16*  rWp1     = (u16*)alloc(524288 * 2);
    u16*  rWp2     = (u16*)alloc(524288 * 2);
    u16*  rWp3     = (u16*)alloc(524288 * 2);
    u16*  rFin     = (u16*)alloc(16384 * 2);
    if (off > ws_size) return;

    RepArgs R;
    R.W01 = W01; R.Wp[0] = Wpost1; R.Wp[1] = Wpost2; R.Wp[2] = Wpost3;
    R.pre[0] = W00; R.pre[1] = Wpre1; R.pre[2] = Wpre2; R.pre[3] = Wpre3;
    R.fin = Wfin;
    R.bias[0] = b00;   R.bias[1] = b01;
    R.bias[2] = bpre1; R.bias[3] = bpost1;
    R.bias[4] = bpre2; R.bias[5] = bpost2;
    R.bias[6] = bpre3; R.bias[7] = bpost3;
    R.bias[8] = bfin;
    R.rPre = rPre; R.rW01 = rW01;
    R.rWp[0] = rWp1; R.rWp[1] = rWp2; R.rWp[2] = rWp3;
    R.rFin = rFin; R.cbias = cbias;

    hipMemsetAsync(gcnt, 0, 256 * 4, stream);
    prepA_kernel<<<373, 256, 0, stream>>>(input, gcnt, perm2, R);

    MainP P;
    P.rPre = rPre; P.rW01 = rW01; P.rWp1 = rWp1; P.rWp2 = rWp2; P.rWp3 = rWp3;
    P.rFin = rFin; P.cbias = cbias;
    main_kernel<<<MAXTILE, 512, 0, stream>>>(input, gcnt, perm2, P, d_out);
}

// Round 4
// 188.896 us; speedup vs baseline: 1.2083x; 1.0127x over previous
//
#include <hip/hip_runtime.h>

#define NB 32768
#define MAXTILE 768
#define ROWS 64
#define NT 4

typedef short s8v __attribute__((ext_vector_type(8)));   // 8 x bf16 bits (4 VGPR)
typedef short s4v __attribute__((ext_vector_type(4)));
typedef float f4v __attribute__((ext_vector_type(4)));
typedef unsigned short u16;
typedef unsigned short u16x4 __attribute__((ext_vector_type(4)));
typedef unsigned int u32;
typedef unsigned char u8;

__device__ __forceinline__ float bf2f(u16 u) { return __uint_as_float(((u32)u) << 16); }
__device__ __forceinline__ u16 f2bf(float f) {
    u32 x = __float_as_uint(f);
    x += 0x7FFFu + ((x >> 16) & 1u);   // RNE
    return (u16)(x >> 16);
}
__device__ __forceinline__ s8v ld8(const u16* p) { return *reinterpret_cast<const s8v*>(p); }

#define MFMA16(a, b, c) __builtin_amdgcn_mfma_f32_16x16x32_bf16((a), (b), (c), 0, 0, 0)

template <int N> struct IC { static constexpr int v = N; };

// dtype probe, done locally per block (wave 0 ballot -> LDS). bf16=1, f32=0.
__device__ __forceinline__ void detect_flag(const void* input, int tid, int* shflag)
{
    if (tid < 64) {
        u32 w = ((const u32*)input)[tid];
        u32 h0 = w & 0xFFFFu;
        u32 e0 = (h0 >> 7) & 0xFFu;
        bool plaus = (h0 == 0u) || (e0 >= 96u && e0 <= 143u);
        unsigned long long m = __ballot(plaus);
        if (tid == 0) *shflag = (__popcll(m) >= 48) ? 1 : 0;
    }
}

// ---------------------------------------------------------------------------
// dispatch A: blocks [0,128): per-block key count (LDS) -> one global
// atomicAdd per (block,key) reserves a contiguous rank range in gcnt ->
// rows scattered straight into perm2[key*512 + rank]. Additionally converts
// this block's 256 rows of features into a packed bf16 buffer feats16[row][128]
// (main then gathers bf16 directly: no f2bf in the hot loop, half the bytes).
// gcnt must be zeroed by a preceding hipMemsetAsync.
// blocks [128,373): weight repack to A-frag layout + bias conversion.
// ---------------------------------------------------------------------------
struct RepArgs {
    const void* W01; const void* Wp[3]; const void* pre[4]; const void* fin;
    const void* bias[9];
    u16 *rPre, *rW01, *rWp[3], *rFin, *cbias;
};

__global__ __launch_bounds__(256) void prepA_kernel(const void* __restrict__ inputv,
                                                    int* __restrict__ gcnt,       // [256]
                                                    int* __restrict__ perm2,      // [256][512]
                                                    u16* __restrict__ feats16,    // [NB][128]
                                                    RepArgs R)
{
    __shared__ int lcnt[256];
    __shared__ int sBase[256];
    __shared__ u16 T[8192];
    __shared__ int shmisc;
    int tid = threadIdx.x;
    int b = blockIdx.x;
    detect_flag(inputv, tid, &shmisc);
    __syncthreads();
    int flag = shmisc;

    if (b < 128) {
        lcnt[tid] = 0;
        __syncthreads();
        int row = (b << 8) + tid;
        const u32* in32 = (const u32*)inputv;
        const u16* in16 = (const u16*)inputv;
        int key = 0;
        if (flag) {
#pragma unroll
            for (int j = 0; j < 4; j++) {
                u16x4 v = *(const u16x4*)(in16 + row * 144 + 128 + j * 4);
                int m = v[1] ? 1 : (v[2] ? 2 : (v[3] ? 3 : 0));
                key |= m << (j << 1);
            }
        } else {
#pragma unroll
            for (int j = 0; j < 4; j++) {
                const u32* p = in32 + row * 144 + 128 + j * 4;
                u32 v1 = p[1], v2 = p[2], v3 = p[3];
                int m = v1 ? 1 : (v2 ? 2 : (v3 ? 3 : 0));
                key |= m << (j << 1);
            }
        }
        int loc = atomicAdd(&lcnt[key], 1);
        __syncthreads();
        int c = lcnt[tid];
        sBase[tid] = c ? atomicAdd(&gcnt[tid], c) : 0;   // device-scope reservation
        __syncthreads();
        int slot = sBase[key] + loc;
        if (slot < 512) perm2[(key << 9) + slot] = row;  // cap guard (stat. impossible)

        // ---- feature conversion: rows [b*256, b*256+256) -> feats16
        int r0 = b << 8;
        if (flag) {
            for (int i = tid; i < 256 * 16; i += 256) {      // 16B chunks
                int r = r0 + (i >> 4), j = (i & 15) << 3;
                *(s8v*)(feats16 + ((size_t)r << 7) + j) = ld8(in16 + (size_t)r * 144 + j);
            }
        } else {
            for (int i = tid; i < 256 * 32; i += 256) {      // 4-float chunks
                int r = r0 + (i >> 5), j = (i & 31) << 2;
                f4v f = *(const f4v*)(in32 + (size_t)r * 144 + j);
                s4v p;
#pragma unroll
                for (int q = 0; q < 4; q++) p[q] = (short)f2bf(f[q]);
                *(s4v*)(feats16 + ((size_t)r << 7) + j) = p;
            }
        }
        return;
    }

    // ---- repack path
    int rb = b - 128;
    const void* src = nullptr; u16* dst = nullptr; int K = 0, k0 = 0, mrow = 0;
    if (rb < 32) {
        int m = rb >> 3, s = rb & 7;
        src = R.W01; dst = R.rW01 + (m * 8 + s) * 8192; K = 256; k0 = s * 32; mrow = m;
    } else if (rb < 224) {
        int idx = rb - 32, mat = idx >> 6, r = idx & 63, m = r >> 4, s = r & 15;
        src = R.Wp[mat]; dst = R.rWp[mat] + (m * 16 + s) * 8192; K = 512; k0 = s * 32; mrow = m;
    } else if (rb < 240) {
        int idx = rb - 224, mat = idx >> 2, m = idx & 3;
        src = R.pre[mat]; dst = R.rPre + (mat * 4 + m) * 8192; K = 32; k0 = 0; mrow = m;
    } else if (rb < 244) {
        int m = rb - 240;   // Wfin [m][256][8] -> [m][s8][lane][8], rows l16>=8 zero
        const u16* s16 = (const u16*)R.fin;
        const float* s32 = (const float*)R.fin;
        for (int i = tid; i < 2048; i += 256) {
            int si = (m * 256 + (i >> 3)) * 8 + (i & 7);
            T[i] = flag ? s16[si] : f2bf(s32[si]);
        }
        __syncthreads();
        u16* d = R.rFin + m * 4096;
        for (int i = tid; i < 4096; i += 256) {
            int s = i >> 9, lane = (i >> 3) & 63, j = i & 7;
            int q = lane >> 4, l16 = lane & 15;
            int k = s * 32 + q * 8 + j;
            d[i] = (l16 < 8) ? T[k * 8 + l16] : (u16)0;
        }
        return;
    } else {
        const int sz[9] = {1024,1024,1024,1024,1024,1024,1024,1024,32};
        const int of[9] = {0,1024,2048,3072,4096,5120,6144,7168,8192};
        for (int i = tid; i < 8224; i += 256) {
            int t = i, e = 0;
            while (t >= sz[e]) { t -= sz[e]; e++; }
            R.cbias[of[e] + t] = flag ? ((const u16*)R.bias[e])[t]
                                      : f2bf(((const float*)R.bias[e])[t]);
        }
        return;
    }
    const u16* s16 = (const u16*)src;
    const float* s32 = (const float*)src;
    for (int i = tid; i < 8192; i += 256) {
        int k = i >> 8, n = i & 255;
        int srcIdx = (mrow * K + k0 + k) * 256 + n;
        T[i] = flag ? s16[srcIdx] : f2bf(s32[srcIdx]);
    }
    __syncthreads();
    for (int i = tid; i < 8192; i += 256) {
        int mt = i >> 9, lane = (i >> 3) & 63, j = i & 7;
        int k = ((lane >> 4) << 3) + j, n = (mt << 4) + (lane & 15);
        dst[i] = T[(k << 8) + n];
    }
}

// ---------------------------------------------------------------------------
// main: one block = 64 rows through the whole net (T-formulation).
// 8 waves; wave w: m-tiles {2w,2w+1} x 4 n-tiles. Fused K=512 gemm, depth-4
// weight prefetch issued before the barrier. XCD-aware tile swizzle.
//
// xh is stored FRAGMENT-ORDERED: xhB[(rowtile nt*16 + kblock sb)*512 +
// lane*8 + j], so the K-loop B-read is one contiguous 1KB ds_read_b128 per
// wave -> zero read bank conflicts (old row-major layout: stride 536 u16,
// quads aliased the same banks -> 6.0M conflict cycles/dispatch).
// Writers map (row, k) -> (nt, sb=k>>5, quad'=(k>>3)&3, j=k&7); for this
// wave's tiles sb is the constant w (hq) / 8+w (hp) and the in-block offset
// is stA = ((quad>>1)*16+l16)*8 + (quad&1)*4 (+256 for ci=1).
// ---------------------------------------------------------------------------
struct MainP { const u16 *rPre, *rW01, *rWp1, *rWp2, *rWp3, *rFin, *cbias, *feats; };

__global__ __launch_bounds__(512, 4) void main_kernel(
    const void* __restrict__ inRaw,
    const int* __restrict__ gcnt, const int* __restrict__ perm2,
    MainP P, void* __restrict__ outp)
{
    __shared__ __align__(16) u16 xhB[32768];   // [nt*16+sb][64 lanes][8]
    __shared__ int rowids[ROWS];
    __shared__ int shflag;
    __shared__ int sMeta[4];   // key, tau, tot, ttot

    int tid = threadIdx.x;
    int lane = tid & 63, w = tid >> 6, quad = lane >> 4, l16 = lane & 15;

    int b = blockIdx.x;
    int t = ((b & 7) * (MAXTILE / 8)) + (b >> 3);   // XCD-contiguous tile runs

    detect_flag(inRaw, tid, &shflag);

    // ---- prologue: wave-0 shuffle scan over per-key tile counts
    if (tid < 64) {
        int4 g = *(const int4*)(gcnt + tid * 4);
        int tot4[4] = {g.x, g.y, g.z, g.w};
        int tiles4[4], lsum = 0;
#pragma unroll
        for (int j = 0; j < 4; j++) { tiles4[j] = (tot4[j] + 63) >> 6; lsum += tiles4[j]; }
        int pre = lsum;
#pragma unroll
        for (int off = 1; off < 64; off <<= 1) {
            int v = __shfl_up(pre, off, 64);
            if (tid >= off) pre += v;
        }
        int run = pre - lsum;            // exclusive base for this lane's 4 keys
#pragma unroll
        for (int j = 0; j < 4; j++) {
            if (t >= run && t < run + tiles4[j]) {   // exactly one (lane,j) matches
                sMeta[0] = tid * 4 + j;  // key
                sMeta[1] = t - run;      // tau
                sMeta[2] = tot4[j];      // tot
            }
            run += tiles4[j];
        }
        if (tid == 63) sMeta[3] = pre;   // total tiles
    }
    __syncthreads();
    if (t >= sMeta[3]) return;           // block-uniform exit
    int key = sMeta[0], tau = sMeta[1], tot = sMeta[2];
    int cntIn = tot - tau * ROWS; if (cntIn > ROWS) cntIn = ROWS;
    if (tid < ROWS) {
        int g = tid < cntIn ? tid : cntIn - 1;   // clamp partial tile (dups benign)
        rowids[tid] = perm2[(key << 9) + tau * ROWS + g];
    }
    __syncthreads();

    int flag = shflag;
    int rows_[NT];
#pragma unroll
    for (int nt = 0; nt < NT; nt++) rows_[nt] = rowids[nt * 16 + l16];

    const u16* feats = P.feats;
    int mt0 = w << 1, mt1 = mt0 + 1;
    int stA = ((quad >> 1) * 16 + l16) * 8 + (quad & 1) * 4;   // store sub-addr

    f4v acc0[NT], acc1[NT];

    // N-slice fused GEMM: A prefetch window depth 4, first loads issued
    // BEFORE the hp-visibility barrier (A-frags don't depend on xhB).
    auto gemm_run = [&](auto nc, const u16* Ab, int ks0) {
        constexpr int N = decltype(nc)::v;
        constexpr int D = 4;
        const u16* base0 = Ab + mt0 * 512 + lane * 8;
        const u16* base1 = Ab + mt1 * 512 + lane * 8;
        s8v A0[D], A1[D];
#pragma unroll
        for (int d = 0; d < D && d < N; d++) {
            A0[d] = ld8(base0 + d * 8192);
            A1[d] = ld8(base1 + d * 8192);
        }
        __syncthreads();                     // hp/hq now visible; prefetch in flight
        __builtin_amdgcn_s_setprio(1);
#pragma unroll
        for (int s = 0; s < N; s++) {
            s8v c0 = A0[s % D], c1 = A1[s % D];
            if (s + D < N) {
                A0[s % D] = ld8(base0 + (s + D) * 8192);
                A1[s % D] = ld8(base1 + (s + D) * 8192);
            }
#pragma unroll
            for (int nt = 0; nt < NT; nt++) {
                s8v B = ld8(&xhB[((nt * 16 + ks0 + s) << 9) + lane * 8]);   // contiguous 1KB
                acc0[nt] = MFMA16(c0, B, acc0[nt]);
                acc1[nt] = MFMA16(c1, B, acc1[nt]);
            }
        }
        __builtin_amdgcn_s_setprio(0);
    };

    for (int node = 0; node < 4; node++) {
        int m = (key >> (node << 1)) & 3;

        // ---- feats B-frags: packed bf16 gather (16B/thread, consumed now)
        s8v fb[NT];
#pragma unroll
        for (int nt = 0; nt < NT; nt++)
            fb[nt] = ld8(feats + ((size_t)rows_[nt] << 7) + (node << 5) + (quad << 3));

        // ---- hp^T = relu(Wpre^T @ feats^T + bpre) -> xhB k-blocks [8+w]
        const u16* preB = P.rPre + ((node << 2) + m) * 8192;
#pragma unroll
        for (int ci = 0; ci < 2; ci++) {
            int mt = mt0 + ci;
            s8v a = ld8(preB + mt * 512 + lane * 8);
            u16x4 bv = *(const u16x4*)(P.cbias + node * 2048 + m * 256 + mt * 16 + quad * 4);
            f4v bias;
#pragma unroll
            for (int r = 0; r < 4; r++) bias[r] = bf2f(bv[r]);
#pragma unroll
            for (int nt = 0; nt < NT; nt++) {
                f4v c = MFMA16(a, fb[nt], bias);
                s4v p;
#pragma unroll
                for (int r = 0; r < 4; r++) { float v = c[r] > 0.f ? c[r] : 0.f; p[r] = (short)f2bf(v); }
                *(s4v*)&xhB[(((nt * 16 + 8 + w) << 9)) + ci * 256 + stA] = p;
            }
        }

        // ---- acc init with bpost
        {
            u16x4 b0 = *(const u16x4*)(P.cbias + node * 2048 + 1024 + m * 256 + mt0 * 16 + quad * 4);
            u16x4 b1 = *(const u16x4*)(P.cbias + node * 2048 + 1024 + m * 256 + mt1 * 16 + quad * 4);
            f4v f0, f1;
#pragma unroll
            for (int r = 0; r < 4; r++) { f0[r] = bf2f(b0[r]); f1[r] = bf2f(b1[r]); }
#pragma unroll
            for (int nt = 0; nt < NT; nt++) { acc0[nt] = f0; acc1[nt] = f1; }
        }

        // ---- fused K-loop (barrier inside gemm_run, after prefetch issue)
        if (node == 0) gemm_run(IC<8>{},  P.rW01 + m * 8 * 8192, 8);
        else {
            const u16* WB = (node == 1 ? P.rWp1 : (node == 2 ? P.rWp2 : P.rWp3)) + m * 16 * 8192;
            gemm_run(IC<16>{}, WB, 0);
        }
        __syncthreads();                       // all xhB reads of this node done

        // ---- relu + write hq^T -> xhB k-blocks [w]
#pragma unroll
        for (int ci = 0; ci < 2; ci++) {
#pragma unroll
            for (int nt = 0; nt < NT; nt++) {
                f4v a = ci ? acc1[nt] : acc0[nt];
                s4v p;
#pragma unroll
                for (int r = 0; r < 4; r++) { float v = a[r] > 0.f ? a[r] : 0.f; p[r] = (short)f2bf(v); }
                *(s4v*)&xhB[((nt * 16 + w) << 9) + ci * 256 + stA] = p;
            }
        }
    }
    __syncthreads();

    // ---- final: out^T = Wfin^T @ x3^T + bfin (waves 0..NT-1)
    if (w < NT) {
        int m3 = (key >> 6) & 3;
        f4v c;
#pragma unroll
        for (int r = 0; r < 4; r++)
            c[r] = (quad < 2) ? bf2f(P.cbias[8192 + m3 * 8 + quad * 4 + r]) : 0.f;
#pragma unroll
        for (int s = 0; s < 8; s++) {
            s8v A = ld8(P.rFin + m3 * 4096 + s * 512 + lane * 8);
            s8v B = ld8(&xhB[((w * 16 + s) << 9) + lane * 8]);
            c = MFMA16(A, B, c);
        }
        int bidx = w * 16 + l16;
        if (quad < 2 && bidx < cntIn) {
            int row = rowids[bidx];
            if (flag) {
                s4v p;
#pragma unroll
                for (int r = 0; r < 4; r++) p[r] = (short)f2bf(c[r]);
                *(s4v*)((u16*)outp + row * 8 + quad * 4) = p;
            } else {
                *(f4v*)((float*)outp + row * 8 + quad * 4) = c;
            }
        }
    }
}

// ---------------------------------------------------------------------------
extern "C" void kernel_launch(void* const* d_in, const int* in_sizes, int n_in,
                              void* d_out, int out_size, void* d_ws, size_t ws_size,
                              hipStream_t stream)
{
    (void)in_sizes; (void)n_in; (void)out_size;
    const void* input  = d_in[0];
    const void* W00    = d_in[1];
    const void* b00    = d_in[2];
    const void* W01    = d_in[3];
    const void* b01    = d_in[4];
    const void* Wpre1  = d_in[5];
    const void* bpre1  = d_in[6];
    const void* Wpost1 = d_in[7];
    const void* bpost1 = d_in[8];
    const void* Wpre2  = d_in[9];
    const void* bpre2  = d_in[10];
    const void* Wpost2 = d_in[11];
    const void* bpost2 = d_in[12];
    const void* Wpre3  = d_in[13];
    const void* bpre3  = d_in[14];
    const void* Wpost3 = d_in[15];
    const void* bpost3 = d_in[16];
    const void* Wfin   = d_in[17];
    const void* bfin   = d_in[18];

    char* base = (char*)d_ws;
    size_t off = 0;
    auto alloc = [&](size_t bytes) -> char* {
        char* p = base + off;
        off += (bytes + 255) & ~(size_t)255;
        return p;
    };
    int*  gcnt      = (int*)alloc(256 * 4);
    int*  perm2     = (int*)alloc(256 * 512 * 4);
    u16*  feats16   = (u16*)alloc((size_t)NB * 128 * 2);
    u16*  cbias    = (u16*)alloc(8224 * 2);
    u16*  rPre     = (u16*)alloc(131072 * 2);
    u16*  rW01     = (u16*)alloc(262144 * 2);
    u16*  rWp1     = (u16*)alloc(524288 * 2);
    u16*  rWp2     = (u16*)alloc(524288 * 2);
    u16*  rWp3     = (u16*)alloc(524288 * 2);
    u16*  rFin     = (u16*)alloc(16384 * 2);
    if (off > ws_size) return;

    RepArgs R;
    R.W01 = W01; R.Wp[0] = Wpost1; R.Wp[1] = Wpost2; R.Wp[2] = Wpost3;
    R.pre[0] = W00; R.pre[1] = Wpre1; R.pre[2] = Wpre2; R.pre[3] = Wpre3;
    R.fin = Wfin;
    R.bias[0] = b00;   R.bias[1] = b01;
    R.bias[2] = bpre1; R.bias[3] = bpost1;
    R.bias[4] = bpre2; R.bias[5] = bpost2;
    R.bias[6] = bpre3; R.bias[7] = bpost3;
    R.bias[8] = bfin;
    R.rPre = rPre; R.rW01 = rW01;
    R.rWp[0] = rWp1; R.rWp[1] = rWp2; R.rWp[2] = rWp3;
    R.rFin = rFin; R.cbias = cbias;

    hipMemsetAsync(gcnt, 0, 256 * 4, stream);
    prepA_kernel<<<373, 256, 0, stream>>>(input, gcnt, perm2, feats16, R);

    MainP P;
    P.rPre = rPre; P.rW01 = rW01; P.rWp1 = rWp1; P.rWp2 = rWp2; P.rWp3 = rWp3;
    P.rFin = rFin; P.cbias = cbias; P.feats = feats16;
    main_kernel<<<MAXTILE, 512, 0, stream>>>(input, gcnt, perm2, P, d_out);
}